// Round 4
// baseline (79.310 us; speedup 1.0000x reference)
//
#include <hip/hip_runtime.h>
#include <math.h>

// Problem constants (fixed by setup_inputs()):
#define BATCH   16
#define NQ      4096      // shape_query pts per batch
#define NPRIOR  1024      // prior pts per batch
#define NREC    5120      // reconstructed = concat(shape_query, prior)
#define NMODEL  4096      // model pts per batch
#define NHYP    64

// Fused-chamfer decomposition:
#define SLICES  16                  // ref-dimension split per query tile
#define BLK     128                 // 2 waves per block
#define QPL     8                   // query points per lane
#define QTILE   (BLK*QPL)           // 1024 queries per block (divides 5120 & 4096)
#define QT1     (NREC/QTILE)        // 5 query tiles (dir1, per batch)
#define QT2     (NMODEL/QTILE)      // 4 query tiles (dir2, per batch)
#define RS1     (NMODEL/SLICES)     // 256 refs per slice (dir1)
#define RS2     (NREC/SLICES)       // 320 refs per slice (dir2)
#define NQD1    (BATCH*NREC)        // 81920 dir1 queries
#define NQD2    (BATCH*NMODEL)      // 65536 dir2 queries
#define WS_WORDS (NQD1+NQD2)        // 147456 uint mins
#define WS_TOTAL_BYTES ((size_t)(WS_WORDS+1)*4)   // + completion counter
#define RED_BLOCKS 128

// Order-preserving float<->uint map so atomicMin on uint == min on float.
__device__ __forceinline__ unsigned f2ord(float f) {
    unsigned b = __float_as_uint(f);
    return (b & 0x80000000u) ? ~b : (b | 0x80000000u);
}
__device__ __forceinline__ float ord2f(unsigned u) {
    return (u & 0x80000000u) ? __uint_as_float(u & 0x7fffffffu)
                             : __uint_as_float(~u);
}

// Single-instruction 3-input min (VOP3; no literal operands used).
__device__ __forceinline__ float min3f(float a, float b, float c) {
    float d;
    asm("v_min3_f32 %0, %1, %2, %3" : "=v"(d) : "v"(a), "v"(b), "v"(c));
    return d;
}

// ---------------- fused path (needs d_ws >= WS_TOTAL_BYTES) ----------------

__global__ __launch_bounds__(256) void init_ws(unsigned int* __restrict__ ws,
                                               float* __restrict__ out) {
    int i = blockIdx.x * 256 + threadIdx.x;
    if (i == 0) { out[2] = 0.0f; out[3] = 0.0f; ws[WS_WORDS] = 0u; }
    if (i < WS_WORDS) ws[i] = 0xFFFFFFFFu;
}

__global__ __launch_bounds__(BLK, 4) void chamfer_main(
    const float* __restrict__ shape_query,
    const float* __restrict__ prior,
    const float* __restrict__ model,
    unsigned int* __restrict__ ws) {
    __shared__ float4 refs[RS2];  // 320 * 16B = 5 KB

    int id = blockIdx.x;
    int dir, b, qt, s;
    if (id < BATCH * QT1 * SLICES) {
        dir = 0;
        b = id / (QT1 * SLICES);
        int r = id % (QT1 * SLICES);
        qt = r / SLICES; s = r % SLICES;
    } else {
        int j = id - BATCH * QT1 * SLICES;
        dir = 1;
        b = j / (QT2 * SLICES);
        int r = j % (QT2 * SLICES);
        qt = r / SLICES; s = r % SLICES;
    }

    const int tid = threadIdx.x;
    const int rcount = (dir == 0) ? RS1 : RS2;
    const int rbase  = s * rcount;

    // Stage this block's ref slice into LDS as (x,y,z,||r||^2).
    for (int i = tid; i < rcount; i += BLK) {
        int j = rbase + i;
        const float* p;
        if (dir == 0) {
            p = model + ((size_t)b * NMODEL + j) * 3;
        } else {
            p = (j < NQ) ? shape_query + ((size_t)b * NQ + j) * 3
                         : prior + ((size_t)b * NPRIOR + (j - NQ)) * 3;
        }
        float x = p[0], y = p[1], z = p[2];
        float nb = fmaf(z, z, fmaf(y, y, x * x));
        refs[i] = make_float4(x, y, z, nb);
    }

    // Load 8 query points per lane; fold the -2 into the coords.
    float qx2[QPL], qy2[QPL], qz2[QPL], mn[QPL];
    const int nq_per_batch = (dir == 0) ? NREC : NMODEL;
#pragma unroll
    for (int q = 0; q < QPL; ++q) {
        int j = qt * QTILE + q * BLK + tid;  // index within batch
        const float* p;
        if (dir == 0) {
            p = (j < NQ) ? shape_query + ((size_t)b * NQ + j) * 3
                         : prior + ((size_t)b * NPRIOR + (j - NQ)) * 3;
        } else {
            p = model + ((size_t)b * NMODEL + j) * 3;
        }
        qx2[q] = -2.0f * p[0]; qy2[q] = -2.0f * p[1]; qz2[q] = -2.0f * p[2];
        mn[q]  = 3.0e38f;
    }

    __syncthreads();

    // Software-pipelined inner loop: 4-ref chunks, double-buffered in
    // registers. Prefetch chunk m+4 from LDS while computing chunk m
    // (112 VALU instrs per chunk hide the LDS latency). 3.5 VALU/pair.
#define COMPUTE4(c0, c1, c2, c3)                                          \
    _Pragma("unroll")                                                     \
    for (int q = 0; q < QPL; ++q) {                                       \
        float x = qx2[q], y = qy2[q], z = qz2[q];                         \
        float d0 = fmaf(z, c0.z, fmaf(y, c0.y, fmaf(x, c0.x, c0.w)));     \
        float d1 = fmaf(z, c1.z, fmaf(y, c1.y, fmaf(x, c1.x, c1.w)));     \
        float d2 = fmaf(z, c2.z, fmaf(y, c2.y, fmaf(x, c2.x, c2.w)));     \
        float d3 = fmaf(z, c3.z, fmaf(y, c3.y, fmaf(x, c3.x, c3.w)));     \
        float t0 = min3f(d0, d1, d2);                                     \
        mn[q] = min3f(mn[q], t0, d3);                                     \
    }

    {
        float4 c0 = refs[0], c1 = refs[1], c2 = refs[2], c3 = refs[3];
#pragma unroll 2
        for (int m = 0; m < rcount - 4; m += 4) {
            float4 n0 = refs[m + 4], n1 = refs[m + 5];
            float4 n2 = refs[m + 6], n3 = refs[m + 7];
            COMPUTE4(c0, c1, c2, c3)
            c0 = n0; c1 = n1; c2 = n2; c3 = n3;
        }
        COMPUTE4(c0, c1, c2, c3)
    }
#undef COMPUTE4

    unsigned int* wsd = ws + ((dir == 0) ? 0 : NQD1);
    const int qgbase = b * nq_per_batch + qt * QTILE;
#pragma unroll
    for (int q = 0; q < QPL; ++q) {
        // ||q||^2 = 0.25 * (qx2^2 + qy2^2 + qz2^2)
        float nq2 = fmaf(qz2[q], qz2[q],
                    fmaf(qy2[q], qy2[q], qx2[q] * qx2[q])) * 0.25f;
        float v = mn[q] + nq2;
        atomicMin(&wsd[qgbase + q * BLK + tid], f2ord(v));
    }
}

// Sums the min arrays; the LAST block to finish also computes the pose loss
// and writes all 5 outputs (saves a separate finalize launch).
__global__ __launch_bounds__(256) void reduce_finalize(
    const unsigned int* __restrict__ ws, const float* __restrict__ logits,
    float* __restrict__ out, unsigned int* __restrict__ counter) {
    float s1 = 0.0f, s2 = 0.0f;
    for (int i = blockIdx.x * 256 + threadIdx.x; i < WS_WORDS;
         i += RED_BLOCKS * 256) {
        float v = ord2f(ws[i]);
        if (i < NQD1) s1 += v; else s2 += v;
    }
#pragma unroll
    for (int off = 32; off > 0; off >>= 1) {
        s1 += __shfl_xor(s1, off, 64);
        s2 += __shfl_xor(s2, off, 64);
    }
    __shared__ float a1[4], a2[4];
    __shared__ int last;
    int w = threadIdx.x >> 6;
    if ((threadIdx.x & 63) == 0) { a1[w] = s1; a2[w] = s2; }
    __syncthreads();
    if (threadIdx.x == 0) {
        atomicAdd(&out[2], a1[0] + a1[1] + a1[2] + a1[3]);
        atomicAdd(&out[3], a2[0] + a2[1] + a2[2] + a2[3]);
        __threadfence();
        unsigned done = atomicAdd(counter, 1u);
        last = (done == RED_BLOCKS - 1) ? 1 : 0;
    }
    __syncthreads();
    if (last) {
        const int lane = threadIdx.x;
        if (lane < 64) {
            float pose_part = 0.0f;
            if (lane < BATCH) {
                const float* L = logits + lane * NHYP;
                float mx = L[0];
#pragma unroll 8
                for (int j = 1; j < NHYP; ++j) mx = fmaxf(mx, L[j]);
                float s = 0.0f;
#pragma unroll 8
                for (int j = 0; j < NHYP; ++j) s += expf(L[j] - mx);
                pose_part = L[0] - (mx + logf(s));  // log_prob[b, 0]
            }
#pragma unroll
            for (int off = 8; off > 0; off >>= 1)
                pose_part += __shfl_xor(pose_part, off, 64);
            if (lane == 0) {
                // Atomic reads (device-scope, L2-coherent) of the final sums.
                float sum1 = atomicAdd(&out[2], 0.0f);
                float sum2 = atomicAdd(&out[3], 0.0f);
                float mean1 = sum1 / (float)NQD1;
                float mean2 = sum2 / (float)NQD2;
                float shape_loss = mean1 + mean2;
                float pose_loss = -pose_part / (float)BATCH;
                out[0] = 0.4f * pose_loss + 0.6f * shape_loss;
                out[1] = pose_loss;
                out[2] = shape_loss;
                out[3] = shape_loss;  // sdf_loss
                out[4] = shape_loss;  // caption_loss
            }
        }
    }
}

// ---------------- fallback path (no / small d_ws) ----------------

__global__ void init_out(float* out) {
    if (threadIdx.x == 0) { out[2] = 0.0f; out[3] = 0.0f; }
}

__device__ __forceinline__ void scan_refs(const float* __restrict__ r, int cnt,
                                          float px, float py, float pz,
                                          float& minv) {
    for (int m = 0; m < cnt; m += 8) {
#pragma unroll
        for (int u = 0; u < 8; ++u) {
            float mx = r[(m + u) * 3 + 0];
            float my = r[(m + u) * 3 + 1];
            float mz = r[(m + u) * 3 + 2];
            float dx = px - mx, dy = py - my, dz = pz - mz;
            float d = fmaf(dz, dz, fmaf(dy, dy, dx * dx));
            minv = fminf(minv, d);
        }
    }
}

__global__ __launch_bounds__(64) void chamfer_sum(
    const float* __restrict__ qa, int na_, const float* __restrict__ qb, int nb_,
    const float* __restrict__ ra, int ma, const float* __restrict__ rb, int mb,
    float* __restrict__ accum) {
    const int b = blockIdx.y;
    const int n = blockIdx.x * 64 + threadIdx.x;
    float px, py, pz;
    if (n < na_) {
        const float* p = qa + ((size_t)b * na_ + n) * 3;
        px = p[0]; py = p[1]; pz = p[2];
    } else {
        const float* p = qb + ((size_t)b * nb_ + (n - na_)) * 3;
        px = p[0]; py = p[1]; pz = p[2];
    }
    float minv = 3.0e38f;
    scan_refs(ra + (size_t)b * ma * 3, ma, px, py, pz, minv);
    if (mb > 0) scan_refs(rb + (size_t)b * mb * 3, mb, px, py, pz, minv);
    float s = minv;
#pragma unroll
    for (int off = 32; off > 0; off >>= 1) s += __shfl_xor(s, off, 64);
    if (threadIdx.x == 0) atomicAdd(accum, s);
}

__global__ __launch_bounds__(64) void finalize_kernel(
    const float* __restrict__ logits, float* __restrict__ out) {
    const int lane = threadIdx.x;
    float pose_part = 0.0f;
    if (lane < BATCH) {
        const float* L = logits + lane * NHYP;
        float mx = L[0];
#pragma unroll 8
        for (int j = 1; j < NHYP; ++j) mx = fmaxf(mx, L[j]);
        float s = 0.0f;
#pragma unroll 8
        for (int j = 0; j < NHYP; ++j) s += expf(L[j] - mx);
        pose_part = L[0] - (mx + logf(s));
    }
#pragma unroll
    for (int off = 8; off > 0; off >>= 1) pose_part += __shfl_xor(pose_part, off, 64);
    if (lane == 0) {
        float mean1 = out[2] / (float)NQD1;
        float mean2 = out[3] / (float)NQD2;
        float shape_loss = mean1 + mean2;
        float pose_loss = -pose_part / (float)BATCH;
        out[0] = 0.4f * pose_loss + 0.6f * shape_loss;
        out[1] = pose_loss;
        out[2] = shape_loss;
        out[3] = shape_loss;
        out[4] = shape_loss;
    }
}

extern "C" void kernel_launch(void* const* d_in, const int* in_sizes, int n_in,
                              void* d_out, int out_size, void* d_ws, size_t ws_size,
                              hipStream_t stream) {
    const float* shape_query = (const float*)d_in[0];  // (16,4096,3)
    const float* logits      = (const float*)d_in[1];  // (16,64)
    const float* prior       = (const float*)d_in[5];  // (16,1024,3)
    const float* model       = (const float*)d_in[6];  // (16,4096,3)
    float* out = (float*)d_out;

    if (ws_size >= WS_TOTAL_BYTES) {
        unsigned int* ws = (unsigned int*)d_ws;
        hipLaunchKernelGGL(init_ws, dim3((WS_WORDS + 256) / 256), dim3(256), 0,
                           stream, ws, out);
        const int nblocks = BATCH * QT1 * SLICES + BATCH * QT2 * SLICES;  // 2304
        hipLaunchKernelGGL(chamfer_main, dim3(nblocks), dim3(BLK), 0, stream,
                           shape_query, prior, model, ws);
        hipLaunchKernelGGL(reduce_finalize, dim3(RED_BLOCKS), dim3(256), 0,
                           stream, ws, logits, out, ws + WS_WORDS);
    } else {
        hipLaunchKernelGGL(init_out, dim3(1), dim3(64), 0, stream, out);
        hipLaunchKernelGGL(chamfer_sum,
                           dim3(NREC / 64, BATCH), dim3(64), 0, stream,
                           shape_query, NQ, prior, NPRIOR,
                           model, NMODEL, (const float*)nullptr, 0, out + 2);
        hipLaunchKernelGGL(chamfer_sum,
                           dim3(NMODEL / 64, BATCH), dim3(64), 0, stream,
                           model, NMODEL, (const float*)nullptr, 0,
                           shape_query, NQ, prior, NPRIOR, out + 3);
        hipLaunchKernelGGL(finalize_kernel, dim3(1), dim3(64), 0, stream,
                           logits, out);
    }
}

// Round 5
// 65.629 us; speedup vs baseline: 1.2085x; 1.2085x over previous
//
#include <hip/hip_runtime.h>
#include <math.h>

// Problem constants (fixed by setup_inputs()):
#define BATCH   16
#define NQ      4096      // shape_query pts per batch
#define NPRIOR  1024      // prior pts per batch
#define NREC    5120      // reconstructed = concat(shape_query, prior)
#define NMODEL  4096      // model pts per batch
#define NHYP    64

#define NQD1    (BATCH*NREC)        // 81920 row-mins (dist1)
#define NQD2    (BATCH*NMODEL)      // 65536 col-mins (dist2)
#define WS_WORDS (NQD1+NQD2)        // 147456 uint mins
#define WS_TOTAL_BYTES ((size_t)(WS_WORDS+1)*4)   // + completion counter
#define RED_BLOCKS 128

// MFMA tiling: per block = 256 rows x 1024 cols (4 subtiles of 256 cols).
#define ROWSTRIPS (NREC/256)            // 20
#define COLBLKS   (NMODEL/1024)         // 4
#define MFMA_BLOCKS (BATCH*ROWSTRIPS*COLBLKS)  // 1280

typedef _Float16 half8 __attribute__((ext_vector_type(8)));
typedef float    f32x4 __attribute__((ext_vector_type(4)));

// Order-preserving float<->uint map so atomicMin on uint == min on float.
__device__ __forceinline__ unsigned f2ord(float f) {
    unsigned b = __float_as_uint(f);
    return (b & 0x80000000u) ? ~b : (b | 0x80000000u);
}
__device__ __forceinline__ float ord2f(unsigned u) {
    return (u & 0x80000000u) ? __uint_as_float(u & 0x7fffffffu)
                             : __uint_as_float(~u);
}

// Single-instruction 3-input min (VOP3).
__device__ __forceinline__ float min3f(float a, float b, float c) {
    float d;
    asm("v_min3_f32 %0, %1, %2, %3" : "=v"(d) : "v"(a), "v"(b), "v"(c));
    return d;
}

// ---------------- fused MFMA path (needs d_ws >= WS_TOTAL_BYTES) ----------------

__global__ __launch_bounds__(256) void init_ws(unsigned int* __restrict__ ws,
                                               float* __restrict__ out) {
    int i = blockIdx.x * 256 + threadIdx.x;
    if (i == 0) { out[2] = 0.0f; out[3] = 0.0f; ws[WS_WORDS] = 0u; }
    if (i < WS_WORDS) ws[i] = 0xFFFFFFFFu;
}

// D[n,m] = nq[n] + nr[m] - 2 q.r  via one f16 MFMA pass (norms folded into K).
// Row-mins -> ws[0..NQD1), col-mins -> ws[NQD1..).
__global__ __launch_bounds__(256) void chamfer_mfma(
    const float* __restrict__ shape_query,
    const float* __restrict__ prior,
    const float* __restrict__ model,
    unsigned int* __restrict__ ws) {
    __shared__ half8 Alds[257];     // 256 rows + zero slot
    __shared__ half8 Blds[257];     // 256 cols + zero slot
    __shared__ float colbuf[1024];  // 4 waves x 256 col partials

    const int blk = blockIdx.x;
    const int b   = blk / (ROWSTRIPS * COLBLKS);
    const int rem = blk % (ROWSTRIPS * COLBLKS);
    const int rs  = rem / COLBLKS;       // row strip (0..19)
    const int cb  = rem % COLBLKS;       // col block (0..3)
    const int rowbase  = rs * 256;
    const int colbase0 = cb * 1024;

    const int t    = threadIdx.x;
    const int wave = t >> 6;
    const int lane = t & 63;
    const int l15  = lane & 15;
    const int kgrp = lane >> 4;

    // ---- stage A (once): (-2x,-2y,-2z, nq, 1, 0,0,0) per row ----
    {
        int g = rowbase + t;
        const float* p = (g < NQ)
            ? shape_query + ((size_t)b * NQ + g) * 3
            : prior + ((size_t)b * NPRIOR + (g - NQ)) * 3;
        float x = p[0], y = p[1], z = p[2];
        float nq = fmaf(z, z, fmaf(y, y, x * x));
        half8 v;
        v[0] = (_Float16)(-2.0f * x); v[1] = (_Float16)(-2.0f * y);
        v[2] = (_Float16)(-2.0f * z); v[3] = (_Float16)nq;
        v[4] = (_Float16)1.0f; v[5] = (_Float16)0.0f;
        v[6] = (_Float16)0.0f; v[7] = (_Float16)0.0f;
        Alds[t] = v;
        if (t == 0) {
            half8 zz;
#pragma unroll
            for (int i = 0; i < 8; ++i) zz[i] = (_Float16)0.0f;
            Alds[256] = zz; Blds[256] = zz;
        }
    }
    __syncthreads();

    // A fragments: lanes with kgrp==0 carry k=0..7; others read the zero slot.
    half8 af[4];
    f32x4 rmn[4];
#pragma unroll
    for (int rt = 0; rt < 4; ++rt) {
        af[rt] = Alds[(kgrp == 0) ? (wave * 64 + rt * 16 + l15) : 256];
#pragma unroll
        for (int i = 0; i < 4; ++i) rmn[rt][i] = 3.0e38f;
    }

    f32x4 cz;
#pragma unroll
    for (int i = 0; i < 4; ++i) cz[i] = 0.0f;

    for (int s = 0; s < 4; ++s) {
        // ---- stage B subtile: (x,y,z, 1, nr, 0,0,0) per col ----
        {
            int g = colbase0 + s * 256 + t;
            const float* p = model + ((size_t)b * NMODEL + g) * 3;
            float x = p[0], y = p[1], z = p[2];
            float nr = fmaf(z, z, fmaf(y, y, x * x));
            half8 v;
            v[0] = (_Float16)x; v[1] = (_Float16)y; v[2] = (_Float16)z;
            v[3] = (_Float16)1.0f; v[4] = (_Float16)nr;
            v[5] = (_Float16)0.0f; v[6] = (_Float16)0.0f; v[7] = (_Float16)0.0f;
            Blds[t] = v;
        }
        __syncthreads();  // B ready (also: previous colbuf fully consumed)

        float colmn[16];
#pragma unroll
        for (int c = 0; c < 16; ++c) colmn[c] = 3.0e38f;

#pragma unroll
        for (int ct = 0; ct < 16; ct += 2) {
            half8 bf0 = Blds[(kgrp == 0) ? (ct * 16 + l15) : 256];
            half8 bf1 = Blds[(kgrp == 0) ? ((ct + 1) * 16 + l15) : 256];
#pragma unroll
            for (int rt = 0; rt < 4; ++rt) {
                f32x4 d0 = __builtin_amdgcn_mfma_f32_16x16x32_f16(af[rt], bf0, cz, 0, 0, 0);
                f32x4 d1 = __builtin_amdgcn_mfma_f32_16x16x32_f16(af[rt], bf1, cz, 0, 0, 0);
                // row-min accumulate (rows = kgrp*4+i of this rt)
                rmn[rt][0] = min3f(rmn[rt][0], d0[0], d1[0]);
                rmn[rt][1] = min3f(rmn[rt][1], d0[1], d1[1]);
                rmn[rt][2] = min3f(rmn[rt][2], d0[2], d1[2]);
                rmn[rt][3] = min3f(rmn[rt][3], d0[3], d1[3]);
                // col-min accumulate (col = l15 of tile ct / ct+1)
                float t0 = min3f(d0[0], d0[1], d0[2]);
                colmn[ct]     = min3f(colmn[ct], t0, d0[3]);
                float t1 = min3f(d1[0], d1[1], d1[2]);
                colmn[ct + 1] = min3f(colmn[ct + 1], t1, d1[3]);
            }
        }

        // col reduce across kgrp (rows within wave), stash per-wave partials.
#pragma unroll
        for (int c = 0; c < 16; ++c) {
            float v = colmn[c];
            v = fminf(v, __shfl_xor(v, 16, 64));
            v = fminf(v, __shfl_xor(v, 32, 64));
            if (lane < 16) colbuf[wave * 256 + c * 16 + lane] = v;
        }
        __syncthreads();  // colbuf ready (also: all MFMA reads of Blds done)

        // combine 4 waves, one atomic per col
        {
            float v = fminf(fminf(colbuf[t], colbuf[256 + t]),
                            fminf(colbuf[512 + t], colbuf[768 + t]));
            int gcol = colbase0 + s * 256 + t;
            atomicMin(&ws[NQD1 + b * NMODEL + gcol], f2ord(v));
        }
    }

    // ---- row flush: butterfly over cols (lane&15), one atomic per row ----
#pragma unroll
    for (int rt = 0; rt < 4; ++rt) {
#pragma unroll
        for (int i = 0; i < 4; ++i) {
            float v = rmn[rt][i];
            v = fminf(v, __shfl_xor(v, 1, 64));
            v = fminf(v, __shfl_xor(v, 2, 64));
            v = fminf(v, __shfl_xor(v, 4, 64));
            v = fminf(v, __shfl_xor(v, 8, 64));
            if (l15 == 0) {
                int grow = rowbase + wave * 64 + rt * 16 + kgrp * 4 + i;
                atomicMin(&ws[b * NREC + grow], f2ord(v));
            }
        }
    }
}

// Sums the min arrays; the LAST block also computes pose loss and writes out.
__global__ __launch_bounds__(256) void reduce_finalize(
    const unsigned int* __restrict__ ws, const float* __restrict__ logits,
    float* __restrict__ out, unsigned int* __restrict__ counter) {
    float s1 = 0.0f, s2 = 0.0f;
    for (int i = blockIdx.x * 256 + threadIdx.x; i < WS_WORDS;
         i += RED_BLOCKS * 256) {
        float v = ord2f(ws[i]);
        if (i < NQD1) s1 += v; else s2 += v;
    }
#pragma unroll
    for (int off = 32; off > 0; off >>= 1) {
        s1 += __shfl_xor(s1, off, 64);
        s2 += __shfl_xor(s2, off, 64);
    }
    __shared__ float a1[4], a2[4];
    __shared__ int last;
    int w = threadIdx.x >> 6;
    if ((threadIdx.x & 63) == 0) { a1[w] = s1; a2[w] = s2; }
    __syncthreads();
    if (threadIdx.x == 0) {
        atomicAdd(&out[2], a1[0] + a1[1] + a1[2] + a1[3]);
        atomicAdd(&out[3], a2[0] + a2[1] + a2[2] + a2[3]);
        __threadfence();
        unsigned done = atomicAdd(counter, 1u);
        last = (done == RED_BLOCKS - 1) ? 1 : 0;
    }
    __syncthreads();
    if (last) {
        const int lane = threadIdx.x;
        if (lane < 64) {
            float pose_part = 0.0f;
            if (lane < BATCH) {
                const float* L = logits + lane * NHYP;
                float mx = L[0];
#pragma unroll 8
                for (int j = 1; j < NHYP; ++j) mx = fmaxf(mx, L[j]);
                float s = 0.0f;
#pragma unroll 8
                for (int j = 0; j < NHYP; ++j) s += expf(L[j] - mx);
                pose_part = L[0] - (mx + logf(s));  // log_prob[b, 0]
            }
#pragma unroll
            for (int off = 8; off > 0; off >>= 1)
                pose_part += __shfl_xor(pose_part, off, 64);
            if (lane == 0) {
                float sum1 = atomicAdd(&out[2], 0.0f);
                float sum2 = atomicAdd(&out[3], 0.0f);
                float mean1 = sum1 / (float)NQD1;
                float mean2 = sum2 / (float)NQD2;
                float shape_loss = mean1 + mean2;
                float pose_loss = -pose_part / (float)BATCH;
                out[0] = 0.4f * pose_loss + 0.6f * shape_loss;
                out[1] = pose_loss;
                out[2] = shape_loss;
                out[3] = shape_loss;  // sdf_loss
                out[4] = shape_loss;  // caption_loss
            }
        }
    }
}

// ---------------- fallback path (no / small d_ws) ----------------

__global__ void init_out(float* out) {
    if (threadIdx.x == 0) { out[2] = 0.0f; out[3] = 0.0f; }
}

__device__ __forceinline__ void scan_refs(const float* __restrict__ r, int cnt,
                                          float px, float py, float pz,
                                          float& minv) {
    for (int m = 0; m < cnt; m += 8) {
#pragma unroll
        for (int u = 0; u < 8; ++u) {
            float mx = r[(m + u) * 3 + 0];
            float my = r[(m + u) * 3 + 1];
            float mz = r[(m + u) * 3 + 2];
            float dx = px - mx, dy = py - my, dz = pz - mz;
            float d = fmaf(dz, dz, fmaf(dy, dy, dx * dx));
            minv = fminf(minv, d);
        }
    }
}

__global__ __launch_bounds__(64) void chamfer_sum(
    const float* __restrict__ qa, int na_, const float* __restrict__ qb, int nb_,
    const float* __restrict__ ra, int ma, const float* __restrict__ rb, int mb,
    float* __restrict__ accum) {
    const int b = blockIdx.y;
    const int n = blockIdx.x * 64 + threadIdx.x;
    float px, py, pz;
    if (n < na_) {
        const float* p = qa + ((size_t)b * na_ + n) * 3;
        px = p[0]; py = p[1]; pz = p[2];
    } else {
        const float* p = qb + ((size_t)b * nb_ + (n - na_)) * 3;
        px = p[0]; py = p[1]; pz = p[2];
    }
    float minv = 3.0e38f;
    scan_refs(ra + (size_t)b * ma * 3, ma, px, py, pz, minv);
    if (mb > 0) scan_refs(rb + (size_t)b * mb * 3, mb, px, py, pz, minv);
    float s = minv;
#pragma unroll
    for (int off = 32; off > 0; off >>= 1) s += __shfl_xor(s, off, 64);
    if (threadIdx.x == 0) atomicAdd(accum, s);
}

__global__ __launch_bounds__(64) void finalize_kernel(
    const float* __restrict__ logits, float* __restrict__ out) {
    const int lane = threadIdx.x;
    float pose_part = 0.0f;
    if (lane < BATCH) {
        const float* L = logits + lane * NHYP;
        float mx = L[0];
#pragma unroll 8
        for (int j = 1; j < NHYP; ++j) mx = fmaxf(mx, L[j]);
        float s = 0.0f;
#pragma unroll 8
        for (int j = 0; j < NHYP; ++j) s += expf(L[j] - mx);
        pose_part = L[0] - (mx + logf(s));
    }
#pragma unroll
    for (int off = 8; off > 0; off >>= 1) pose_part += __shfl_xor(pose_part, off, 64);
    if (lane == 0) {
        float mean1 = out[2] / (float)NQD1;
        float mean2 = out[3] / (float)NQD2;
        float shape_loss = mean1 + mean2;
        float pose_loss = -pose_part / (float)BATCH;
        out[0] = 0.4f * pose_loss + 0.6f * shape_loss;
        out[1] = pose_loss;
        out[2] = shape_loss;
        out[3] = shape_loss;
        out[4] = shape_loss;
    }
}

extern "C" void kernel_launch(void* const* d_in, const int* in_sizes, int n_in,
                              void* d_out, int out_size, void* d_ws, size_t ws_size,
                              hipStream_t stream) {
    const float* shape_query = (const float*)d_in[0];  // (16,4096,3)
    const float* logits      = (const float*)d_in[1];  // (16,64)
    const float* prior       = (const float*)d_in[5];  // (16,1024,3)
    const float* model       = (const float*)d_in[6];  // (16,4096,3)
    float* out = (float*)d_out;

    if (ws_size >= WS_TOTAL_BYTES) {
        unsigned int* ws = (unsigned int*)d_ws;
        hipLaunchKernelGGL(init_ws, dim3((WS_WORDS + 256) / 256), dim3(256), 0,
                           stream, ws, out);
        hipLaunchKernelGGL(chamfer_mfma, dim3(MFMA_BLOCKS), dim3(256), 0, stream,
                           shape_query, prior, model, ws);
        hipLaunchKernelGGL(reduce_finalize, dim3(RED_BLOCKS), dim3(256), 0,
                           stream, ws, logits, out, ws + WS_WORDS);
    } else {
        hipLaunchKernelGGL(init_out, dim3(1), dim3(64), 0, stream, out);
        hipLaunchKernelGGL(chamfer_sum,
                           dim3(NREC / 64, BATCH), dim3(64), 0, stream,
                           shape_query, NQ, prior, NPRIOR,
                           model, NMODEL, (const float*)nullptr, 0, out + 2);
        hipLaunchKernelGGL(chamfer_sum,
                           dim3(NMODEL / 64, BATCH), dim3(64), 0, stream,
                           model, NMODEL, (const float*)nullptr, 0,
                           shape_query, NQ, prior, NPRIOR, out + 3);
        hipLaunchKernelGGL(finalize_kernel, dim3(1), dim3(64), 0, stream,
                           logits, out);
    }
}

// Round 6
// 56.965 us; speedup vs baseline: 1.3923x; 1.1521x over previous
//
#include <hip/hip_runtime.h>
#include <math.h>

// Problem constants (fixed by setup_inputs()):
#define BATCH   16
#define NQ      4096      // shape_query pts per batch
#define NPRIOR  1024      // prior pts per batch
#define NREC    5120      // reconstructed = concat(shape_query, prior)
#define NMODEL  4096      // model pts per batch
#define NHYP    64

#define NQD1    (BATCH*NREC)        // 81920 row queries (dist1)
#define NQD2    (BATCH*NMODEL)      // 65536 col queries (dist2)

// ---- new partials path (no atomics, no init kernel) ----
#define ROWSTRIPS (NREC/256)             // 20 row strips per batch
#define COLBLKS   (NMODEL/1024)          // 4 col blocks per batch
#define GBLOCKS   (BATCH*ROWSTRIPS*COLBLKS)  // 1280
#define ROWPART_WORDS (COLBLKS*NQD1)     // 327680
#define COLPART_WORDS (ROWSTRIPS*NQD2)   // 1310720
#define WS_NEW_WORDS  (ROWPART_WORDS + COLPART_WORDS + 1)   // + counter
#define WS_NEW_BYTES  ((size_t)WS_NEW_WORDS*4)              // ~6.55 MB
#define RED_BLOCKS 128

// ---- old fused path (round-5; used if ws too small for partials) ----
#define OLD_WS_WORDS (NQD1+NQD2)
#define OLD_WS_BYTES ((size_t)(OLD_WS_WORDS+1)*4)
#define OLD_ROWSTRIPS 20
#define OLD_COLBLKS 4
#define OLD_MFMA_BLOCKS (BATCH*OLD_ROWSTRIPS*OLD_COLBLKS)

typedef _Float16 half8  __attribute__((ext_vector_type(8)));
typedef float    f32x4  __attribute__((ext_vector_type(4)));
typedef float    f32x16 __attribute__((ext_vector_type(16)));

// Order-preserving float<->uint map so atomicMin on uint == min on float.
__device__ __forceinline__ unsigned f2ord(float f) {
    unsigned b = __float_as_uint(f);
    return (b & 0x80000000u) ? ~b : (b | 0x80000000u);
}
__device__ __forceinline__ float ord2f(unsigned u) {
    return (u & 0x80000000u) ? __uint_as_float(u & 0x7fffffffu)
                             : __uint_as_float(~u);
}

// Single-instruction 3-input min (VOP3).
__device__ __forceinline__ float min3f(float a, float b, float c) {
    float d;
    asm("v_min3_f32 %0, %1, %2, %3" : "=v"(d) : "v"(a), "v"(b), "v"(c));
    return d;
}

// ================= NEW PATH =================
// D[n,m] = nq[n] + nr[m] - 2 q.r via 32x32x16 f16 MFMA (norms folded into K).
// Per block: 256 rows x 1024 cols; one barrier after staging; barrier-free
// hot loop per wave (64 rows x 1024 cols each). Row/col minima written as
// per-block partial planes in ws (no global atomics, no init needed).
__global__ __launch_bounds__(256) void chamfer_mfma32(
    const float* __restrict__ shape_query,
    const float* __restrict__ prior,
    const float* __restrict__ model,
    float* __restrict__ ws, float* __restrict__ out) {
    __shared__ half8 Alds[257];         // 256 rows + zero slot
    __shared__ half8 Blds[1025];        // 1024 cols + zero slot
    __shared__ unsigned colbuf[1024];   // cross-wave col mins (ord-encoded)

    const int blk = blockIdx.x;
    if (blk == 0 && threadIdx.x == 0) {
        out[2] = 0.0f; out[3] = 0.0f;   // reduce kernel runs after us
        ((unsigned*)ws)[ROWPART_WORDS + COLPART_WORDS] = 0u;  // counter
    }

    const int b   = blk / (ROWSTRIPS * COLBLKS);
    const int rem = blk % (ROWSTRIPS * COLBLKS);
    const int rs  = rem / COLBLKS;       // row strip (0..19)
    const int cb  = rem % COLBLKS;       // col block (0..3)
    const int rowbase = rs * 256;
    const int colbase = cb * 1024;

    const int t    = threadIdx.x;
    const int wave = t >> 6;
    const int lane = t & 63;
    const int l31  = lane & 31;
    const int kh   = lane >> 5;          // 0: k=0..7 data, 1: k=8..15 zeros

    // ---- stage A (once): (-2x,-2y,-2z, nq, 1, 0,0,0) per row ----
    {
        int g = rowbase + t;
        const float* p = (g < NQ)
            ? shape_query + ((size_t)b * NQ + g) * 3
            : prior + ((size_t)b * NPRIOR + (g - NQ)) * 3;
        float x = p[0], y = p[1], z = p[2];
        float nq = fmaf(z, z, fmaf(y, y, x * x));
        half8 v;
        v[0] = (_Float16)(-2.0f * x); v[1] = (_Float16)(-2.0f * y);
        v[2] = (_Float16)(-2.0f * z); v[3] = (_Float16)nq;
        v[4] = (_Float16)1.0f; v[5] = (_Float16)0.0f;
        v[6] = (_Float16)0.0f; v[7] = (_Float16)0.0f;
        Alds[t] = v;
    }
    // ---- stage B (once): (x,y,z, 1, nr, 0,0,0) per col; init colbuf ----
#pragma unroll
    for (int k = 0; k < 4; ++k) {
        int c = t + k * 256;
        const float* p = model + ((size_t)b * NMODEL + colbase + c) * 3;
        float x = p[0], y = p[1], z = p[2];
        float nr = fmaf(z, z, fmaf(y, y, x * x));
        half8 v;
        v[0] = (_Float16)x; v[1] = (_Float16)y; v[2] = (_Float16)z;
        v[3] = (_Float16)1.0f; v[4] = (_Float16)nr;
        v[5] = (_Float16)0.0f; v[6] = (_Float16)0.0f; v[7] = (_Float16)0.0f;
        Blds[c] = v;
        colbuf[c] = 0xFFFFFFFFu;
    }
    if (t == 0) {
        half8 zz;
#pragma unroll
        for (int i = 0; i < 8; ++i) zz[i] = (_Float16)0.0f;
        Alds[256] = zz; Blds[1024] = zz;
    }
    __syncthreads();   // the ONLY barrier before the epilogue

    // A fragments for this wave's 64 rows (two 32-row tiles), kept in regs.
    half8 af0 = Alds[kh ? 256 : (wave * 64 + l31)];
    half8 af1 = Alds[kh ? 256 : (wave * 64 + 32 + l31)];

    float rmn0[16], rmn1[16];
#pragma unroll
    for (int r = 0; r < 16; ++r) { rmn0[r] = 3.0e38f; rmn1[r] = 3.0e38f; }

    f32x16 cz;
#pragma unroll
    for (int i = 0; i < 16; ++i) cz[i] = 0.0f;

    // Hot loop: 32 col-tiles, barrier-free, B-frag prefetched one ahead.
    half8 bf = Blds[kh ? 1024 : l31];
#pragma unroll 2
    for (int ct = 0; ct < 32; ++ct) {
        half8 bfn = Blds[kh ? 1024 : ((((ct + 1) & 31) * 32) + l31)];
        f32x16 d0 = __builtin_amdgcn_mfma_f32_32x32x16_f16(af0, bf, cz, 0, 0, 0);
        f32x16 d1 = __builtin_amdgcn_mfma_f32_32x32x16_f16(af1, bf, cz, 0, 0, 0);
        // row-min accumulate: reg r of d0/d1 is a distinct row, col=l31.
#pragma unroll
        for (int r = 0; r < 16; ++r) {
            rmn0[r] = fminf(rmn0[r], d0[r]);
            rmn1[r] = fminf(rmn1[r], d1[r]);
        }
        // col-min: tree over the 32 in-lane rows (d0+d1), then lane^32.
        float m0 = min3f(d0[0],  d0[1],  d0[2]);
        float m1 = min3f(d0[3],  d0[4],  d0[5]);
        float m2 = min3f(d0[6],  d0[7],  d0[8]);
        float m3 = min3f(d0[9],  d0[10], d0[11]);
        float m4 = min3f(d0[12], d0[13], d0[14]);
        float m5 = min3f(d0[15], d1[0],  d1[1]);
        float m6 = min3f(d1[2],  d1[3],  d1[4]);
        float m7 = min3f(d1[5],  d1[6],  d1[7]);
        float m8 = min3f(d1[8],  d1[9],  d1[10]);
        float m9 = min3f(d1[11], d1[12], d1[13]);
        float n0 = min3f(m0, m1, m2);
        float n1 = min3f(m3, m4, m5);
        float n2 = min3f(m6, m7, m8);
        float n3 = min3f(m9, d1[14], d1[15]);
        float v  = fminf(min3f(n0, n1, n2), n3);
        v = fminf(v, __shfl_xor(v, 32, 64));
        if (lane < 32) atomicMin(&colbuf[ct * 32 + lane], f2ord(v));
        bf = bfn;
    }

    __syncthreads();   // colbuf complete across the 4 waves

    // ---- col partial plane: [rs][b*NMODEL + colbase + c] ----
    {
        float* colpart = ws + ROWPART_WORDS + (size_t)rs * NQD2
                         + b * NMODEL + colbase;
#pragma unroll
        for (int k = 0; k < 4; ++k) {
            int c = t + k * 256;
            colpart[c] = ord2f(colbuf[c]);
        }
    }

    // ---- row partial plane: butterfly over cols (lane&31) ----
    {
        float* rowpart = ws + (size_t)cb * NQD1 + b * NREC;
#pragma unroll
        for (int hv = 0; hv < 2; ++hv) {
#pragma unroll
            for (int r = 0; r < 16; ++r) {
                float v = hv ? rmn1[r] : rmn0[r];
                v = fminf(v, __shfl_xor(v, 1, 64));
                v = fminf(v, __shfl_xor(v, 2, 64));
                v = fminf(v, __shfl_xor(v, 4, 64));
                v = fminf(v, __shfl_xor(v, 8, 64));
                v = fminf(v, __shfl_xor(v, 16, 64));
                if (l31 == 0) {
                    int row = rowbase + wave * 64 + hv * 32
                              + (r & 3) + 8 * (r >> 2) + 4 * kh;
                    rowpart[row] = v;
                }
            }
        }
    }
}

// Min over partial planes, sum; last block computes pose loss, writes out.
__global__ __launch_bounds__(256) void reduce_finalize2(
    const float* __restrict__ ws, const float* __restrict__ logits,
    float* __restrict__ out, unsigned int* __restrict__ counter) {
    const float* rowpart = ws;
    const float* colpart = ws + ROWPART_WORDS;
    float s1 = 0.0f, s2 = 0.0f;
    const int tot = NQD1 + NQD2;
    for (int i = blockIdx.x * 256 + threadIdx.x; i < tot;
         i += RED_BLOCKS * 256) {
        if (i < NQD1) {
            float v = fminf(fminf(rowpart[i],            rowpart[NQD1 + i]),
                            fminf(rowpart[2 * NQD1 + i], rowpart[3 * NQD1 + i]));
            s1 += v;
        } else {
            int j = i - NQD1;
            float v = colpart[j];
#pragma unroll
            for (int s = 1; s < ROWSTRIPS; ++s)
                v = fminf(v, colpart[(size_t)s * NQD2 + j]);
            s2 += v;
        }
    }
#pragma unroll
    for (int off = 32; off > 0; off >>= 1) {
        s1 += __shfl_xor(s1, off, 64);
        s2 += __shfl_xor(s2, off, 64);
    }
    __shared__ float a1[4], a2[4];
    __shared__ int last;
    int w = threadIdx.x >> 6;
    if ((threadIdx.x & 63) == 0) { a1[w] = s1; a2[w] = s2; }
    __syncthreads();
    if (threadIdx.x == 0) {
        atomicAdd(&out[2], a1[0] + a1[1] + a1[2] + a1[3]);
        atomicAdd(&out[3], a2[0] + a2[1] + a2[2] + a2[3]);
        __threadfence();
        unsigned done = atomicAdd(counter, 1u);
        last = (done == RED_BLOCKS - 1) ? 1 : 0;
    }
    __syncthreads();
    if (last && threadIdx.x < 64) {
        const int lane = threadIdx.x;
        float pose_part = 0.0f;
        if (lane < BATCH) {
            const float* L = logits + lane * NHYP;
            float mx = L[0];
#pragma unroll 8
            for (int j = 1; j < NHYP; ++j) mx = fmaxf(mx, L[j]);
            float s = 0.0f;
#pragma unroll 8
            for (int j = 0; j < NHYP; ++j) s += expf(L[j] - mx);
            pose_part = L[0] - (mx + logf(s));  // log_prob[b, 0]
        }
#pragma unroll
        for (int off = 8; off > 0; off >>= 1)
            pose_part += __shfl_xor(pose_part, off, 64);
        if (lane == 0) {
            float sum1 = atomicAdd(&out[2], 0.0f);
            float sum2 = atomicAdd(&out[3], 0.0f);
            float shape_loss = sum1 / (float)NQD1 + sum2 / (float)NQD2;
            float pose_loss = -pose_part / (float)BATCH;
            out[0] = 0.4f * pose_loss + 0.6f * shape_loss;
            out[1] = pose_loss;
            out[2] = shape_loss;
            out[3] = shape_loss;  // sdf_loss
            out[4] = shape_loss;  // caption_loss
        }
    }
}

// ================= OLD FUSED PATH (round 5, mid-size ws) =================

__global__ __launch_bounds__(256) void init_ws(unsigned int* __restrict__ ws,
                                               float* __restrict__ out) {
    int i = blockIdx.x * 256 + threadIdx.x;
    if (i == 0) { out[2] = 0.0f; out[3] = 0.0f; ws[OLD_WS_WORDS] = 0u; }
    if (i < OLD_WS_WORDS) ws[i] = 0xFFFFFFFFu;
}

__global__ __launch_bounds__(256) void chamfer_mfma(
    const float* __restrict__ shape_query,
    const float* __restrict__ prior,
    const float* __restrict__ model,
    unsigned int* __restrict__ ws) {
    __shared__ half8 AldsO[257];
    __shared__ half8 BldsO[257];
    __shared__ float colbufO[1024];

    const int blk = blockIdx.x;
    const int b   = blk / (OLD_ROWSTRIPS * OLD_COLBLKS);
    const int rem = blk % (OLD_ROWSTRIPS * OLD_COLBLKS);
    const int rs  = rem / OLD_COLBLKS;
    const int cb  = rem % OLD_COLBLKS;
    const int rowbase  = rs * 256;
    const int colbase0 = cb * 1024;

    const int t    = threadIdx.x;
    const int wave = t >> 6;
    const int lane = t & 63;
    const int l15  = lane & 15;
    const int kgrp = lane >> 4;

    {
        int g = rowbase + t;
        const float* p = (g < NQ)
            ? shape_query + ((size_t)b * NQ + g) * 3
            : prior + ((size_t)b * NPRIOR + (g - NQ)) * 3;
        float x = p[0], y = p[1], z = p[2];
        float nq = fmaf(z, z, fmaf(y, y, x * x));
        half8 v;
        v[0] = (_Float16)(-2.0f * x); v[1] = (_Float16)(-2.0f * y);
        v[2] = (_Float16)(-2.0f * z); v[3] = (_Float16)nq;
        v[4] = (_Float16)1.0f; v[5] = (_Float16)0.0f;
        v[6] = (_Float16)0.0f; v[7] = (_Float16)0.0f;
        AldsO[t] = v;
        if (t == 0) {
            half8 zz;
#pragma unroll
            for (int i = 0; i < 8; ++i) zz[i] = (_Float16)0.0f;
            AldsO[256] = zz; BldsO[256] = zz;
        }
    }
    __syncthreads();

    half8 af[4];
    f32x4 rmn[4];
#pragma unroll
    for (int rt = 0; rt < 4; ++rt) {
        af[rt] = AldsO[(kgrp == 0) ? (wave * 64 + rt * 16 + l15) : 256];
#pragma unroll
        for (int i = 0; i < 4; ++i) rmn[rt][i] = 3.0e38f;
    }
    f32x4 cz;
#pragma unroll
    for (int i = 0; i < 4; ++i) cz[i] = 0.0f;

    for (int s = 0; s < 4; ++s) {
        {
            int g = colbase0 + s * 256 + t;
            const float* p = model + ((size_t)b * NMODEL + g) * 3;
            float x = p[0], y = p[1], z = p[2];
            float nr = fmaf(z, z, fmaf(y, y, x * x));
            half8 v;
            v[0] = (_Float16)x; v[1] = (_Float16)y; v[2] = (_Float16)z;
            v[3] = (_Float16)1.0f; v[4] = (_Float16)nr;
            v[5] = (_Float16)0.0f; v[6] = (_Float16)0.0f; v[7] = (_Float16)0.0f;
            BldsO[t] = v;
        }
        __syncthreads();

        float colmn[16];
#pragma unroll
        for (int c = 0; c < 16; ++c) colmn[c] = 3.0e38f;

#pragma unroll
        for (int ct = 0; ct < 16; ct += 2) {
            half8 bf0 = BldsO[(kgrp == 0) ? (ct * 16 + l15) : 256];
            half8 bf1 = BldsO[(kgrp == 0) ? ((ct + 1) * 16 + l15) : 256];
#pragma unroll
            for (int rt = 0; rt < 4; ++rt) {
                f32x4 d0 = __builtin_amdgcn_mfma_f32_16x16x32_f16(af[rt], bf0, cz, 0, 0, 0);
                f32x4 d1 = __builtin_amdgcn_mfma_f32_16x16x32_f16(af[rt], bf1, cz, 0, 0, 0);
                rmn[rt][0] = min3f(rmn[rt][0], d0[0], d1[0]);
                rmn[rt][1] = min3f(rmn[rt][1], d0[1], d1[1]);
                rmn[rt][2] = min3f(rmn[rt][2], d0[2], d1[2]);
                rmn[rt][3] = min3f(rmn[rt][3], d0[3], d1[3]);
                float t0 = min3f(d0[0], d0[1], d0[2]);
                colmn[ct]     = min3f(colmn[ct], t0, d0[3]);
                float t1 = min3f(d1[0], d1[1], d1[2]);
                colmn[ct + 1] = min3f(colmn[ct + 1], t1, d1[3]);
            }
        }

#pragma unroll
        for (int c = 0; c < 16; ++c) {
            float v = colmn[c];
            v = fminf(v, __shfl_xor(v, 16, 64));
            v = fminf(v, __shfl_xor(v, 32, 64));
            if (lane < 16) colbufO[wave * 256 + c * 16 + lane] = v;
        }
        __syncthreads();
        {
            float v = fminf(fminf(colbufO[t], colbufO[256 + t]),
                            fminf(colbufO[512 + t], colbufO[768 + t]));
            int gcol = colbase0 + s * 256 + t;
            atomicMin(&ws[NQD1 + b * NMODEL + gcol], f2ord(v));
        }
    }

#pragma unroll
    for (int rt = 0; rt < 4; ++rt) {
#pragma unroll
        for (int i = 0; i < 4; ++i) {
            float v = rmn[rt][i];
            v = fminf(v, __shfl_xor(v, 1, 64));
            v = fminf(v, __shfl_xor(v, 2, 64));
            v = fminf(v, __shfl_xor(v, 4, 64));
            v = fminf(v, __shfl_xor(v, 8, 64));
            if (l15 == 0) {
                int grow = rowbase + wave * 64 + rt * 16 + kgrp * 4 + i;
                atomicMin(&ws[b * NREC + grow], f2ord(v));
            }
        }
    }
}

__global__ __launch_bounds__(256) void reduce_finalize(
    const unsigned int* __restrict__ ws, const float* __restrict__ logits,
    float* __restrict__ out, unsigned int* __restrict__ counter) {
    float s1 = 0.0f, s2 = 0.0f;
    for (int i = blockIdx.x * 256 + threadIdx.x; i < OLD_WS_WORDS;
         i += RED_BLOCKS * 256) {
        float v = ord2f(ws[i]);
        if (i < NQD1) s1 += v; else s2 += v;
    }
#pragma unroll
    for (int off = 32; off > 0; off >>= 1) {
        s1 += __shfl_xor(s1, off, 64);
        s2 += __shfl_xor(s2, off, 64);
    }
    __shared__ float a1[4], a2[4];
    __shared__ int last;
    int w = threadIdx.x >> 6;
    if ((threadIdx.x & 63) == 0) { a1[w] = s1; a2[w] = s2; }
    __syncthreads();
    if (threadIdx.x == 0) {
        atomicAdd(&out[2], a1[0] + a1[1] + a1[2] + a1[3]);
        atomicAdd(&out[3], a2[0] + a2[1] + a2[2] + a2[3]);
        __threadfence();
        unsigned done = atomicAdd(counter, 1u);
        last = (done == RED_BLOCKS - 1) ? 1 : 0;
    }
    __syncthreads();
    if (last && threadIdx.x < 64) {
        const int lane = threadIdx.x;
        float pose_part = 0.0f;
        if (lane < BATCH) {
            const float* L = logits + lane * NHYP;
            float mx = L[0];
#pragma unroll 8
            for (int j = 1; j < NHYP; ++j) mx = fmaxf(mx, L[j]);
            float s = 0.0f;
#pragma unroll 8
            for (int j = 0; j < NHYP; ++j) s += expf(L[j] - mx);
            pose_part = L[0] - (mx + logf(s));
        }
#pragma unroll
        for (int off = 8; off > 0; off >>= 1)
            pose_part += __shfl_xor(pose_part, off, 64);
        if (lane == 0) {
            float sum1 = atomicAdd(&out[2], 0.0f);
            float sum2 = atomicAdd(&out[3], 0.0f);
            float shape_loss = sum1 / (float)NQD1 + sum2 / (float)NQD2;
            float pose_loss = -pose_part / (float)BATCH;
            out[0] = 0.4f * pose_loss + 0.6f * shape_loss;
            out[1] = pose_loss;
            out[2] = shape_loss;
            out[3] = shape_loss;
            out[4] = shape_loss;
        }
    }
}

// ================= DUMB FALLBACK (tiny ws) =================

__global__ void init_out(float* out) {
    if (threadIdx.x == 0) { out[2] = 0.0f; out[3] = 0.0f; }
}

__device__ __forceinline__ void scan_refs(const float* __restrict__ r, int cnt,
                                          float px, float py, float pz,
                                          float& minv) {
    for (int m = 0; m < cnt; m += 8) {
#pragma unroll
        for (int u = 0; u < 8; ++u) {
            float mx = r[(m + u) * 3 + 0];
            float my = r[(m + u) * 3 + 1];
            float mz = r[(m + u) * 3 + 2];
            float dx = px - mx, dy = py - my, dz = pz - mz;
            float d = fmaf(dz, dz, fmaf(dy, dy, dx * dx));
            minv = fminf(minv, d);
        }
    }
}

__global__ __launch_bounds__(64) void chamfer_sum(
    const float* __restrict__ qa, int na_, const float* __restrict__ qb, int nb_,
    const float* __restrict__ ra, int ma, const float* __restrict__ rb, int mb,
    float* __restrict__ accum) {
    const int b = blockIdx.y;
    const int n = blockIdx.x * 64 + threadIdx.x;
    float px, py, pz;
    if (n < na_) {
        const float* p = qa + ((size_t)b * na_ + n) * 3;
        px = p[0]; py = p[1]; pz = p[2];
    } else {
        const float* p = qb + ((size_t)b * nb_ + (n - na_)) * 3;
        px = p[0]; py = p[1]; pz = p[2];
    }
    float minv = 3.0e38f;
    scan_refs(ra + (size_t)b * ma * 3, ma, px, py, pz, minv);
    if (mb > 0) scan_refs(rb + (size_t)b * mb * 3, mb, px, py, pz, minv);
    float s = minv;
#pragma unroll
    for (int off = 32; off > 0; off >>= 1) s += __shfl_xor(s, off, 64);
    if (threadIdx.x == 0) atomicAdd(accum, s);
}

__global__ __launch_bounds__(64) void finalize_kernel(
    const float* __restrict__ logits, float* __restrict__ out) {
    const int lane = threadIdx.x;
    float pose_part = 0.0f;
    if (lane < BATCH) {
        const float* L = logits + lane * NHYP;
        float mx = L[0];
#pragma unroll 8
        for (int j = 1; j < NHYP; ++j) mx = fmaxf(mx, L[j]);
        float s = 0.0f;
#pragma unroll 8
        for (int j = 0; j < NHYP; ++j) s += expf(L[j] - mx);
        pose_part = L[0] - (mx + logf(s));
    }
#pragma unroll
    for (int off = 8; off > 0; off >>= 1) pose_part += __shfl_xor(pose_part, off, 64);
    if (lane == 0) {
        float shape_loss = out[2] / (float)NQD1 + out[3] / (float)NQD2;
        float pose_loss = -pose_part / (float)BATCH;
        out[0] = 0.4f * pose_loss + 0.6f * shape_loss;
        out[1] = pose_loss;
        out[2] = shape_loss;
        out[3] = shape_loss;
        out[4] = shape_loss;
    }
}

extern "C" void kernel_launch(void* const* d_in, const int* in_sizes, int n_in,
                              void* d_out, int out_size, void* d_ws, size_t ws_size,
                              hipStream_t stream) {
    const float* shape_query = (const float*)d_in[0];  // (16,4096,3)
    const float* logits      = (const float*)d_in[1];  // (16,64)
    const float* prior       = (const float*)d_in[5];  // (16,1024,3)
    const float* model       = (const float*)d_in[6];  // (16,4096,3)
    float* out = (float*)d_out;

    if (ws_size >= WS_NEW_BYTES) {
        float* ws = (float*)d_ws;
        unsigned int* counter =
            (unsigned int*)ws + ROWPART_WORDS + COLPART_WORDS;
        hipLaunchKernelGGL(chamfer_mfma32, dim3(GBLOCKS), dim3(256), 0, stream,
                           shape_query, prior, model, ws, out);
        hipLaunchKernelGGL(reduce_finalize2, dim3(RED_BLOCKS), dim3(256), 0,
                           stream, ws, logits, out, counter);
    } else if (ws_size >= OLD_WS_BYTES) {
        unsigned int* ws = (unsigned int*)d_ws;
        hipLaunchKernelGGL(init_ws, dim3((OLD_WS_WORDS + 256) / 256), dim3(256),
                           0, stream, ws, out);
        hipLaunchKernelGGL(chamfer_mfma, dim3(OLD_MFMA_BLOCKS), dim3(256), 0,
                           stream, shape_query, prior, model, ws);
        hipLaunchKernelGGL(reduce_finalize, dim3(RED_BLOCKS), dim3(256), 0,
                           stream, ws, logits, out, ws + OLD_WS_WORDS);
    } else {
        hipLaunchKernelGGL(init_out, dim3(1), dim3(64), 0, stream, out);
        hipLaunchKernelGGL(chamfer_sum,
                           dim3(NREC / 64, BATCH), dim3(64), 0, stream,
                           shape_query, NQ, prior, NPRIOR,
                           model, NMODEL, (const float*)nullptr, 0, out + 2);
        hipLaunchKernelGGL(chamfer_sum,
                           dim3(NMODEL / 64, BATCH), dim3(64), 0, stream,
                           model, NMODEL, (const float*)nullptr, 0,
                           shape_query, NQ, prior, NPRIOR, out + 3);
        hipLaunchKernelGGL(finalize_kernel, dim3(1), dim3(64), 0, stream,
                           logits, out);
    }
}

// Round 7
// 50.657 us; speedup vs baseline: 1.5656x; 1.1245x over previous
//
#include <hip/hip_runtime.h>
#include <math.h>

// Problem constants (fixed by setup_inputs()):
#define BATCH   16
#define NQ      4096      // shape_query pts per batch
#define NPRIOR  1024      // prior pts per batch
#define NREC    5120      // reconstructed = concat(shape_query, prior)
#define NMODEL  4096      // model pts per batch
#define NHYP    64

#define NQD1    (BATCH*NREC)        // 81920 dist1 outputs (rec side)
#define NQD2    (BATCH*NMODEL)      // 65536 dist2 outputs (model side)

// Two symmetric passes; each computes ONLY row-mins (in-lane reg axis).
// Pass 1: rows=rec(256/block), cols=model(1024/block)  -> 16x20x4 = 1280 blocks
// Pass 2: rows=model(256/block), cols=rec(1280/block)  -> 16x16x4 = 1024 blocks
#define P1_RS   (NREC/256)           // 20
#define P1_CB   (NMODEL/1024)        // 4
#define P1_BLOCKS (BATCH*P1_RS*P1_CB)      // 1280
#define P2_RS   (NMODEL/256)         // 16
#define P2_CB   (NREC/1280)          // 4
#define P2_BLOCKS (BATCH*P2_RS*P2_CB)      // 1024
#define GBLOCKS (P1_BLOCKS + P2_BLOCKS)    // 2304

#define WS_WORDS (P1_CB*NQD1 + P2_CB*NQD2 + 1)  // 589825 (~2.36 MB)
#define WS_BYTES ((size_t)WS_WORDS*4)
#define RED_BLOCKS 128

typedef _Float16 half8  __attribute__((ext_vector_type(8)));
typedef float    f32x16 __attribute__((ext_vector_type(16)));

// Single-instruction 3-input min (VOP3).
__device__ __forceinline__ float min3f(float a, float b, float c) {
    float d;
    asm("v_min3_f32 %0, %1, %2, %3" : "=v"(d) : "v"(a), "v"(b), "v"(c));
    return d;
}

// Pack a point as MFMA-K row: (-2x,-2y,-2z, n, 1, 0,0,0)  ("query" side)
__device__ __forceinline__ half8 packQ(float x, float y, float z) {
    float n = fmaf(z, z, fmaf(y, y, x * x));
    half8 v;
    v[0] = (_Float16)(-2.0f * x); v[1] = (_Float16)(-2.0f * y);
    v[2] = (_Float16)(-2.0f * z); v[3] = (_Float16)n;
    v[4] = (_Float16)1.0f; v[5] = (_Float16)0.0f;
    v[6] = (_Float16)0.0f; v[7] = (_Float16)0.0f;
    return v;
}
// Pack a point as (x,y,z, 1, n, 0,0,0)  ("reference" side)
__device__ __forceinline__ half8 packR(float x, float y, float z) {
    float n = fmaf(z, z, fmaf(y, y, x * x));
    half8 v;
    v[0] = (_Float16)x; v[1] = (_Float16)y; v[2] = (_Float16)z;
    v[3] = (_Float16)1.0f; v[4] = (_Float16)n;
    v[5] = (_Float16)0.0f; v[6] = (_Float16)0.0f; v[7] = (_Float16)0.0f;
    return v;
}

__device__ __forceinline__ const float* rec_ptr(
    const float* __restrict__ shape_query, const float* __restrict__ prior,
    int b, int g) {
    return (g < NQ) ? shape_query + ((size_t)b * NQ + g) * 3
                    : prior + ((size_t)b * NPRIOR + (g - NQ)) * 3;
}

// ================= main pass kernel =================
// D[n,m] = nq[n] + nr[m] - 2 q.r via 32x32x16 f16 MFMA (norms in K-slots).
// Each block: 256 rows x ncols; hot loop = 4 MFMA + 32 v_min3 per col-pair,
// no shfl / no atomics / no barriers inside. Row-min partial plane written.
__global__ __launch_bounds__(256, 4) void chamfer_pass(
    const float* __restrict__ shape_query,
    const float* __restrict__ prior,
    const float* __restrict__ model,
    float* __restrict__ ws, float* __restrict__ out) {
    __shared__ half8 Alds[257];          // 256 rows + zero slot
    __shared__ half8 Blds[1281];         // up to 1280 cols + zero slot

    const int blk = blockIdx.x;
    if (blk == 0 && threadIdx.x == 0) {
        out[2] = 0.0f; out[3] = 0.0f;
        ((unsigned*)ws)[WS_WORDS - 1] = 0u;   // reduce completion counter
    }

    const int t    = threadIdx.x;
    const int wave = t >> 6;
    const int lane = t & 63;
    const int l31  = lane & 31;
    const int kh   = lane >> 5;          // 0: k=0..7 carries data; 1: zeros

    int b, rowbase, colbase, ncols, niters;
    float* rowplane;
    bool pass1 = (blk < P1_BLOCKS);
    if (pass1) {
        b = blk / (P1_RS * P1_CB);
        int rem = blk % (P1_RS * P1_CB);
        int rs = rem / P1_CB, cb = rem % P1_CB;
        rowbase = rs * 256; colbase = cb * 1024;
        ncols = 1024; niters = 16;
        rowplane = ws + (size_t)cb * NQD1 + b * NREC + rowbase;
    } else {
        int j = blk - P1_BLOCKS;
        b = j / (P2_RS * P2_CB);
        int rem = j % (P2_RS * P2_CB);
        int rs = rem / P2_CB, cb = rem % P2_CB;
        rowbase = rs * 256; colbase = cb * 1280;
        ncols = 1280; niters = 20;
        rowplane = ws + (size_t)P1_CB * NQD1 + (size_t)cb * NQD2
                   + b * NMODEL + rowbase;
    }

    // ---- stage A (rows), 1 pt/thread ----
    {
        const float* p = pass1
            ? rec_ptr(shape_query, prior, b, rowbase + t)
            : model + ((size_t)b * NMODEL + rowbase + t) * 3;
        Alds[t] = packQ(p[0], p[1], p[2]);
    }
    // ---- stage B (cols) ----
    for (int c = t; c < ncols; c += 256) {
        const float* p = pass1
            ? model + ((size_t)b * NMODEL + colbase + c) * 3
            : rec_ptr(shape_query, prior, b, colbase + c);
        Blds[c] = packR(p[0], p[1], p[2]);
    }
    if (t == 0) {
        half8 zz;
#pragma unroll
        for (int i = 0; i < 8; ++i) zz[i] = (_Float16)0.0f;
        Alds[256] = zz; Blds[1280] = zz;
    }
    __syncthreads();   // only barrier

    // A fragments: this wave's 64 rows (two 32-row tiles).
    half8 af0 = Alds[kh ? 256 : (wave * 64 + l31)];
    half8 af1 = Alds[kh ? 256 : (wave * 64 + 32 + l31)];

    float rmn0[16], rmn1[16];
#pragma unroll
    for (int r = 0; r < 16; ++r) { rmn0[r] = 3.0e38f; rmn1[r] = 3.0e38f; }

    f32x16 cz;
#pragma unroll
    for (int i = 0; i < 16; ++i) cz[i] = 0.0f;

    // Hot loop over col-tile PAIRS (64 cols/iter): 4 MFMA + 32 v_min3.
    half8 bfa = Blds[kh ? 1280 : l31];
    half8 bfb = Blds[kh ? 1280 : (32 + l31)];
#pragma unroll 2
    for (int it = 0; it < niters; ++it) {
        int nxt = (it + 1 == niters) ? 0 : (it + 1) * 64;
        half8 bfa_n = Blds[kh ? 1280 : (nxt + l31)];
        half8 bfb_n = Blds[kh ? 1280 : (nxt + 32 + l31)];
        f32x16 d0a = __builtin_amdgcn_mfma_f32_32x32x16_f16(af0, bfa, cz, 0, 0, 0);
        f32x16 d0b = __builtin_amdgcn_mfma_f32_32x32x16_f16(af0, bfb, cz, 0, 0, 0);
        f32x16 d1a = __builtin_amdgcn_mfma_f32_32x32x16_f16(af1, bfa, cz, 0, 0, 0);
        f32x16 d1b = __builtin_amdgcn_mfma_f32_32x32x16_f16(af1, bfb, cz, 0, 0, 0);
#pragma unroll
        for (int r = 0; r < 16; ++r) {
            rmn0[r] = min3f(rmn0[r], d0a[r], d0b[r]);
            rmn1[r] = min3f(rmn1[r], d1a[r], d1b[r]);
        }
        bfa = bfa_n; bfb = bfb_n;
    }

    // ---- epilogue: butterfly min over cols (lane&31), write 32 rows ----
#pragma unroll
    for (int hv = 0; hv < 2; ++hv) {
#pragma unroll
        for (int r = 0; r < 16; ++r) {
            float v = hv ? rmn1[r] : rmn0[r];
            v = fminf(v, __shfl_xor(v, 1, 64));
            v = fminf(v, __shfl_xor(v, 2, 64));
            v = fminf(v, __shfl_xor(v, 4, 64));
            v = fminf(v, __shfl_xor(v, 8, 64));
            v = fminf(v, __shfl_xor(v, 16, 64));
            if (l31 == 0) {
                int row = wave * 64 + hv * 32 + (r & 3) + 8 * (r >> 2) + 4 * kh;
                rowplane[row] = v;
            }
        }
    }
}

// Min over the 4 partial planes per side, sum; last block finalizes.
__global__ __launch_bounds__(256) void reduce_finalize2(
    const float* __restrict__ ws, const float* __restrict__ logits,
    float* __restrict__ out, unsigned int* __restrict__ counter) {
    const float* p1 = ws;
    const float* p2 = ws + (size_t)P1_CB * NQD1;
    float s1 = 0.0f, s2 = 0.0f;
    const int tot = NQD1 + NQD2;
    for (int i = blockIdx.x * 256 + threadIdx.x; i < tot;
         i += RED_BLOCKS * 256) {
        if (i < NQD1) {
            s1 += fminf(fminf(p1[i],            p1[NQD1 + i]),
                        fminf(p1[2 * NQD1 + i], p1[3 * NQD1 + i]));
        } else {
            int j = i - NQD1;
            s2 += fminf(fminf(p2[j],            p2[NQD2 + j]),
                        fminf(p2[2 * NQD2 + j], p2[3 * NQD2 + j]));
        }
    }
#pragma unroll
    for (int off = 32; off > 0; off >>= 1) {
        s1 += __shfl_xor(s1, off, 64);
        s2 += __shfl_xor(s2, off, 64);
    }
    __shared__ float a1[4], a2[4];
    __shared__ int last;
    int w = threadIdx.x >> 6;
    if ((threadIdx.x & 63) == 0) { a1[w] = s1; a2[w] = s2; }
    __syncthreads();
    if (threadIdx.x == 0) {
        atomicAdd(&out[2], a1[0] + a1[1] + a1[2] + a1[3]);
        atomicAdd(&out[3], a2[0] + a2[1] + a2[2] + a2[3]);
        __threadfence();
        unsigned done = atomicAdd(counter, 1u);
        last = (done == RED_BLOCKS - 1) ? 1 : 0;
    }
    __syncthreads();
    if (last && threadIdx.x < 64) {
        const int lane = threadIdx.x;
        float pose_part = 0.0f;
        if (lane < BATCH) {
            const float* L = logits + lane * NHYP;
            float mx = L[0];
#pragma unroll 8
            for (int j = 1; j < NHYP; ++j) mx = fmaxf(mx, L[j]);
            float s = 0.0f;
#pragma unroll 8
            for (int j = 0; j < NHYP; ++j) s += expf(L[j] - mx);
            pose_part = L[0] - (mx + logf(s));  // log_prob[b, 0]
        }
#pragma unroll
        for (int off = 8; off > 0; off >>= 1)
            pose_part += __shfl_xor(pose_part, off, 64);
        if (lane == 0) {
            float sum1 = atomicAdd(&out[2], 0.0f);
            float sum2 = atomicAdd(&out[3], 0.0f);
            float shape_loss = sum1 / (float)NQD1 + sum2 / (float)NQD2;
            float pose_loss = -pose_part / (float)BATCH;
            out[0] = 0.4f * pose_loss + 0.6f * shape_loss;
            out[1] = pose_loss;
            out[2] = shape_loss;
            out[3] = shape_loss;  // sdf_loss
            out[4] = shape_loss;  // caption_loss
        }
    }
}

// ================= fallback (tiny ws) =================

__global__ void init_out(float* out) {
    if (threadIdx.x == 0) { out[2] = 0.0f; out[3] = 0.0f; }
}

__device__ __forceinline__ void scan_refs(const float* __restrict__ r, int cnt,
                                          float px, float py, float pz,
                                          float& minv) {
    for (int m = 0; m < cnt; m += 8) {
#pragma unroll
        for (int u = 0; u < 8; ++u) {
            float mx = r[(m + u) * 3 + 0];
            float my = r[(m + u) * 3 + 1];
            float mz = r[(m + u) * 3 + 2];
            float dx = px - mx, dy = py - my, dz = pz - mz;
            float d = fmaf(dz, dz, fmaf(dy, dy, dx * dx));
            minv = fminf(minv, d);
        }
    }
}

__global__ __launch_bounds__(64) void chamfer_sum(
    const float* __restrict__ qa, int na_, const float* __restrict__ qb, int nb_,
    const float* __restrict__ ra, int ma, const float* __restrict__ rb, int mb,
    float* __restrict__ accum) {
    const int b = blockIdx.y;
    const int n = blockIdx.x * 64 + threadIdx.x;
    float px, py, pz;
    if (n < na_) {
        const float* p = qa + ((size_t)b * na_ + n) * 3;
        px = p[0]; py = p[1]; pz = p[2];
    } else {
        const float* p = qb + ((size_t)b * nb_ + (n - na_)) * 3;
        px = p[0]; py = p[1]; pz = p[2];
    }
    float minv = 3.0e38f;
    scan_refs(ra + (size_t)b * ma * 3, ma, px, py, pz, minv);
    if (mb > 0) scan_refs(rb + (size_t)b * mb * 3, mb, px, py, pz, minv);
    float s = minv;
#pragma unroll
    for (int off = 32; off > 0; off >>= 1) s += __shfl_xor(s, off, 64);
    if (threadIdx.x == 0) atomicAdd(accum, s);
}

__global__ __launch_bounds__(64) void finalize_kernel(
    const float* __restrict__ logits, float* __restrict__ out) {
    const int lane = threadIdx.x;
    float pose_part = 0.0f;
    if (lane < BATCH) {
        const float* L = logits + lane * NHYP;
        float mx = L[0];
#pragma unroll 8
        for (int j = 1; j < NHYP; ++j) mx = fmaxf(mx, L[j]);
        float s = 0.0f;
#pragma unroll 8
        for (int j = 0; j < NHYP; ++j) s += expf(L[j] - mx);
        pose_part = L[0] - (mx + logf(s));
    }
#pragma unroll
    for (int off = 8; off > 0; off >>= 1) pose_part += __shfl_xor(pose_part, off, 64);
    if (lane == 0) {
        float shape_loss = out[2] / (float)NQD1 + out[3] / (float)NQD2;
        float pose_loss = -pose_part / (float)BATCH;
        out[0] = 0.4f * pose_loss + 0.6f * shape_loss;
        out[1] = pose_loss;
        out[2] = shape_loss;
        out[3] = shape_loss;
        out[4] = shape_loss;
    }
}

extern "C" void kernel_launch(void* const* d_in, const int* in_sizes, int n_in,
                              void* d_out, int out_size, void* d_ws, size_t ws_size,
                              hipStream_t stream) {
    const float* shape_query = (const float*)d_in[0];  // (16,4096,3)
    const float* logits      = (const float*)d_in[1];  // (16,64)
    const float* prior       = (const float*)d_in[5];  // (16,1024,3)
    const float* model       = (const float*)d_in[6];  // (16,4096,3)
    float* out = (float*)d_out;

    if (ws_size >= WS_BYTES) {
        float* ws = (float*)d_ws;
        unsigned int* counter = (unsigned int*)ws + (WS_WORDS - 1);
        hipLaunchKernelGGL(chamfer_pass, dim3(GBLOCKS), dim3(256), 0, stream,
                           shape_query, prior, model, ws, out);
        hipLaunchKernelGGL(reduce_finalize2, dim3(RED_BLOCKS), dim3(256), 0,
                           stream, ws, logits, out, counter);
    } else {
        hipLaunchKernelGGL(init_out, dim3(1), dim3(64), 0, stream, out);
        hipLaunchKernelGGL(chamfer_sum,
                           dim3(NREC / 64, BATCH), dim3(64), 0, stream,
                           shape_query, NQ, prior, NPRIOR,
                           model, NMODEL, (const float*)nullptr, 0, out + 2);
        hipLaunchKernelGGL(chamfer_sum,
                           dim3(NMODEL / 64, BATCH), dim3(64), 0, stream,
                           model, NMODEL, (const float*)nullptr, 0,
                           shape_query, NQ, prior, NPRIOR, out + 3);
        hipLaunchKernelGGL(finalize_kernel, dim3(1), dim3(64), 0, stream,
                           logits, out);
    }
}